// Round 5
// baseline (487.826 us; speedup 1.0000x reference)
//
#include <hip/hip_runtime.h>

constexpr int N_NODES = 100000;
constexpr int N_EDGES = 1000000;
constexpr int IN_CH   = 64;
constexpr int OUT_CH  = 128;

constexpr int NVX = 8;                       // virtual XCDs
constexpr int NC  = NVX * N_NODES;           // 800000 (vxcd, dst) counters
constexpr int RNODES = 32;                   // dst nodes per agg block (100000/32 exact)

constexpr int SCAN_ELEMS  = 1024;
constexpr int SCAN_BLOCKS = (NC + SCAN_ELEMS - 1) / SCAN_ELEMS;   // 782

// ---------------------------------------------------------------------------
// Phase 1: histogram over (vxcd, dst). vxcd = blockIdx%8 matches bin_kernel.
// ---------------------------------------------------------------------------
__global__ __launch_bounds__(256) void hist_kernel(
    const int* __restrict__ ei, int* __restrict__ count)
{
    int e = blockIdx.x * 256 + threadIdx.x;
    if (e >= N_EDGES) return;
    int vx = blockIdx.x & 7;
    atomicAdd(&count[vx * N_NODES + ei[e]], 1);
}

// ---------------------------------------------------------------------------
// Phase 2: hierarchical exclusive scan of count[0..NC) -> offset[0..NC].
// ---------------------------------------------------------------------------
__global__ __launch_bounds__(256) void scanA_kernel(
    const int* __restrict__ count, int* __restrict__ offset,
    int* __restrict__ partials)
{
    __shared__ int ts[256];
    const int t    = threadIdx.x;
    const int base = blockIdx.x * SCAN_ELEMS + t * 4;

    int v[4], s = 0;
    #pragma unroll
    for (int j = 0; j < 4; ++j) {
        int i = base + j;
        v[j] = (i < NC) ? count[i] : 0;
        s += v[j];
    }
    ts[t] = s;
    __syncthreads();
    for (int off = 1; off < 256; off <<= 1) {
        int add = (t >= off) ? ts[t - off] : 0;
        __syncthreads();
        ts[t] += add;
        __syncthreads();
    }
    int run = ts[t] - s;
    #pragma unroll
    for (int j = 0; j < 4; ++j) {
        int i = base + j;
        if (i < NC) offset[i] = run;
        run += v[j];
    }
    if (t == 255) partials[blockIdx.x] = ts[255];
}

__global__ __launch_bounds__(1024) void scanB_kernel(int* __restrict__ partials)
{
    __shared__ int ts[1024];
    const int t = threadIdx.x;
    int v = (t < SCAN_BLOCKS) ? partials[t] : 0;
    ts[t] = v;
    __syncthreads();
    for (int off = 1; off < 1024; off <<= 1) {
        int add = (t >= off) ? ts[t - off] : 0;
        __syncthreads();
        ts[t] += add;
        __syncthreads();
    }
    if (t < SCAN_BLOCKS) partials[t] = ts[t] - v;   // exclusive
}

__global__ __launch_bounds__(256) void scanC_kernel(
    int* __restrict__ offset, const int* __restrict__ partials)
{
    int i = blockIdx.x * 256 + threadIdx.x;
    if (i < NC) offset[i] += partials[i >> 10];
    if (i == 0) offset[NC] = N_EDGES;
}

// ---------------------------------------------------------------------------
// Phase 3: bin edges into per-(vxcd, dst) segments. Payload packs dstLocal
// (dst&31) into the spare bits above the 17-bit src.
// ---------------------------------------------------------------------------
__global__ __launch_bounds__(256) void bin_kernel(
    const int* __restrict__ ei, const float* __restrict__ ew,
    const int* __restrict__ offset, int* __restrict__ count,
    int2* __restrict__ bucket)
{
    int e = blockIdx.x * 256 + threadIdx.x;
    if (e >= N_EDGES) return;
    int   vx  = blockIdx.x & 7;
    int   dst = ei[e];
    int   src = ei[N_EDGES + e];
    float w   = ew[e];
    int   idx = vx * N_NODES + dst;
    int pos = atomicAdd(&count[idx], -1) - 1;
    bucket[offset[idx] + pos] = make_int2(src | ((dst & 31) << 17),
                                          __float_as_int(w));
}

// ---------------------------------------------------------------------------
// Phase 4: block owns 32 dst nodes; its edges are 8 contiguous bucket spans.
// Stream edges with full waves, accumulate into an LDS tile via ds-atomics,
// write agg coalesced.
// ---------------------------------------------------------------------------
constexpr int ASTR = 66;   // LDS row stride (floats): 2*dstL+c banking, <=2-way

__global__ __launch_bounds__(256) void agg_kernel(
    const float* __restrict__ x, const int2* __restrict__ bucket,
    const int* __restrict__ offset, float* __restrict__ agg)
{
    __shared__ float acc[RNODES * ASTR];      // 8448 B
    __shared__ int   sstart[NVX];
    __shared__ int   spre[NVX + 1];           // prefix of span lengths

    const int t     = threadIdx.x;
    const int rbase = blockIdx.x * RNODES;

    for (int i = t; i < RNODES * ASTR; i += 256) acc[i] = 0.f;

    if (t < NVX) {
        int s = offset[t * N_NODES + rbase];
        int e = offset[t * N_NODES + rbase + RNODES];
        sstart[t] = s;
        spre[t]   = e - s;                    // temporarily length
    }
    __syncthreads();
    if (t == 0) {
        int run = 0;
        #pragma unroll
        for (int vx = 0; vx < NVX; ++vx) {
            int len = spre[vx];
            spre[vx] = run;
            run += len;
        }
        spre[NVX] = run;
    }
    __syncthreads();

    const int tot = spre[NVX];
    const int g   = t >> 4;                   // 16 groups of 16 lanes
    const int c4  = (t & 15) << 2;

    for (int i = g; i < tot; i += 16) {
        // locate span: linear scan over 8 prefix entries (LDS broadcast)
        int vx = 0;
        #pragma unroll
        for (int k = 1; k < NVX; ++k) vx += (i >= spre[k]) ? 1 : 0;
        int j = sstart[vx] + (i - spre[vx]);

        int2  eb   = bucket[j];
        int   src  = eb.x & 0x1FFFF;
        int   dstL = eb.x >> 17;
        float w    = __int_as_float(eb.y);
        float4 v = *reinterpret_cast<const float4*>(x + (size_t)src * IN_CH + c4);
        float* ap = &acc[dstL * ASTR + c4];
        atomicAdd(ap + 0, w * v.x);
        atomicAdd(ap + 1, w * v.y);
        atomicAdd(ap + 2, w * v.z);
        atomicAdd(ap + 3, w * v.w);
    }
    __syncthreads();

    // write out: thread t -> node r = t>>3, 8 channels q*8..q*8+7
    const int r = t >> 3;
    const int q = t & 7;
    const float* src = &acc[r * ASTR + q * 8];
    float4 o0 = make_float4(src[0], src[1], src[2], src[3]);
    float4 o1 = make_float4(src[4], src[5], src[6], src[7]);
    float* dst = agg + (size_t)(rbase + r) * IN_CH + q * 8;
    *reinterpret_cast<float4*>(dst)     = o0;
    *reinterpret_cast<float4*>(dst + 4) = o1;
}

// ---------------------------------------------------------------------------
// Phase 5: out[N,128] = agg[N,64] @ W[128,64]^T + b
// ---------------------------------------------------------------------------
constexpr int LSTR = 66;

__global__ __launch_bounds__(256) void gcn_gemm_kernel(
    const float* __restrict__ agg,
    const float* __restrict__ W,
    const float* __restrict__ b,
    float*       __restrict__ out)
{
    __shared__ float Wl[OUT_CH * LSTR];
    __shared__ float al[32 * LSTR];

    const int t = threadIdx.x;
    const int rbase = blockIdx.x * 32;

    for (int i = t; i < OUT_CH * IN_CH / 4; i += 256) {
        float4 v = reinterpret_cast<const float4*>(W)[i];
        int c = i >> 4;
        int k = (i & 15) << 2;
        float* p = &Wl[c * LSTR + k];
        p[0] = v.x; p[1] = v.y; p[2] = v.z; p[3] = v.w;
    }
    for (int i = t; i < 32 * IN_CH / 4; i += 256) {
        float4 v = reinterpret_cast<const float4*>(agg + (size_t)rbase * IN_CH)[i];
        int r = i >> 4;
        int k = (i & 15) << 2;
        float* p = &al[r * LSTR + k];
        p[0] = v.x; p[1] = v.y; p[2] = v.z; p[3] = v.w;
    }
    __syncthreads();

    const int chT = t & 31;
    const int r0  = (t >> 5) << 2;

    float acc[4][4];
    #pragma unroll
    for (int i = 0; i < 4; ++i)
        #pragma unroll
        for (int j = 0; j < 4; ++j)
            acc[i][j] = 0.f;

    #pragma unroll
    for (int k = 0; k < IN_CH; k += 2) {
        float2 wv[4], av[4];
        #pragma unroll
        for (int j = 0; j < 4; ++j)
            wv[j] = *reinterpret_cast<const float2*>(&Wl[(chT + 32 * j) * LSTR + k]);
        #pragma unroll
        for (int i = 0; i < 4; ++i)
            av[i] = *reinterpret_cast<const float2*>(&al[(r0 + i) * LSTR + k]);
        #pragma unroll
        for (int i = 0; i < 4; ++i)
            #pragma unroll
            for (int j = 0; j < 4; ++j)
                acc[i][j] += av[i].x * wv[j].x + av[i].y * wv[j].y;
    }

    #pragma unroll
    for (int j = 0; j < 4; ++j) {
        int   c  = chT + 32 * j;
        float bc = b[c];
        #pragma unroll
        for (int i = 0; i < 4; ++i) {
            int r = rbase + r0 + i;
            out[(size_t)r * OUT_CH + c] = acc[i][j] + bc;
        }
    }
}

// ---------------------------------------------------------------------------
extern "C" void kernel_launch(void* const* d_in, const int* in_sizes, int n_in,
                              void* d_out, int out_size, void* d_ws, size_t ws_size,
                              hipStream_t stream) {
    const float* x  = (const float*)d_in[0];
    const int*   ei = (const int*)  d_in[1];
    const float* ew = (const float*)d_in[2];
    const float* W  = (const float*)d_in[3];
    const float* b  = (const float*)d_in[4];
    float* out = (float*)d_out;

    char* ws = (char*)d_ws;
    size_t off = 0;
    auto alloc = [&](size_t bytes) {
        char* p = ws + off;
        off += (bytes + 15) & ~size_t(15);
        return p;
    };
    float* agg      = (float*)alloc((size_t)N_NODES * IN_CH * sizeof(float)); // 25.6 MB
    int*   count    = (int*)  alloc((size_t)NC * sizeof(int));                // 3.2 MB
    int*   offset   = (int*)  alloc((size_t)(NC + 1) * sizeof(int));          // 3.2 MB
    int*   partials = (int*)  alloc(1024 * sizeof(int));
    int2*  bucket   = (int2*) alloc((size_t)N_EDGES * sizeof(int2));          // 8 MB

    hipMemsetAsync(count, 0, (size_t)NC * sizeof(int), stream);

    int egrid = (N_EDGES + 255) / 256;
    hist_kernel<<<egrid, 256, 0, stream>>>(ei, count);
    scanA_kernel<<<SCAN_BLOCKS, 256, 0, stream>>>(count, offset, partials);
    scanB_kernel<<<1, 1024, 0, stream>>>(partials);
    scanC_kernel<<<(NC + 255) / 256, 256, 0, stream>>>(offset, partials);
    bin_kernel<<<egrid, 256, 0, stream>>>(ei, ew, offset, count, bucket);

    agg_kernel<<<N_NODES / RNODES, 256, 0, stream>>>(x, bucket, offset, agg);

    gcn_gemm_kernel<<<N_NODES / 32, 256, 0, stream>>>(agg, W, b, out);
}

// Round 6
// 208.905 us; speedup vs baseline: 2.3352x; 2.3352x over previous
//
#include <hip/hip_runtime.h>

constexpr int N_NODES = 100000;
constexpr int N_EDGES = 1000000;
constexpr int IN_CH   = 64;
constexpr int OUT_CH  = 128;

constexpr int NVX = 8;                       // virtual XCDs
constexpr int NC  = NVX * N_NODES;           // 800000 (vxcd, dst) counters

constexpr int SCAN_ELEMS  = 1024;
constexpr int SCAN_BLOCKS = (NC + SCAN_ELEMS - 1) / SCAN_ELEMS;   // 782

// ---------------------------------------------------------------------------
// Phase 1: histogram over (vxcd, dst). vxcd = blockIdx%8 matches bin_kernel.
// ---------------------------------------------------------------------------
__global__ __launch_bounds__(256) void hist_kernel(
    const int* __restrict__ ei, int* __restrict__ count)
{
    int e = blockIdx.x * 256 + threadIdx.x;
    if (e >= N_EDGES) return;
    int vx = blockIdx.x & 7;
    atomicAdd(&count[vx * N_NODES + ei[e]], 1);
}

// ---------------------------------------------------------------------------
// Phase 2: hierarchical exclusive scan of count[0..NC) -> offset[0..NC].
// ---------------------------------------------------------------------------
__global__ __launch_bounds__(256) void scanA_kernel(
    const int* __restrict__ count, int* __restrict__ offset,
    int* __restrict__ partials)
{
    __shared__ int ts[256];
    const int t    = threadIdx.x;
    const int base = blockIdx.x * SCAN_ELEMS + t * 4;

    int v[4], s = 0;
    #pragma unroll
    for (int j = 0; j < 4; ++j) {
        int i = base + j;
        v[j] = (i < NC) ? count[i] : 0;
        s += v[j];
    }
    ts[t] = s;
    __syncthreads();
    for (int off = 1; off < 256; off <<= 1) {
        int add = (t >= off) ? ts[t - off] : 0;
        __syncthreads();
        ts[t] += add;
        __syncthreads();
    }
    int run = ts[t] - s;
    #pragma unroll
    for (int j = 0; j < 4; ++j) {
        int i = base + j;
        if (i < NC) offset[i] = run;
        run += v[j];
    }
    if (t == 255) partials[blockIdx.x] = ts[255];
}

__global__ __launch_bounds__(1024) void scanB_kernel(int* __restrict__ partials)
{
    __shared__ int ts[1024];
    const int t = threadIdx.x;
    int v = (t < SCAN_BLOCKS) ? partials[t] : 0;
    ts[t] = v;
    __syncthreads();
    for (int off = 1; off < 1024; off <<= 1) {
        int add = (t >= off) ? ts[t - off] : 0;
        __syncthreads();
        ts[t] += add;
        __syncthreads();
    }
    if (t < SCAN_BLOCKS) partials[t] = ts[t] - v;   // exclusive
}

__global__ __launch_bounds__(256) void scanC_kernel(
    int* __restrict__ offset, const int* __restrict__ partials)
{
    int i = blockIdx.x * 256 + threadIdx.x;
    if (i < NC) offset[i] += partials[i >> 10];
    if (i == 0) offset[NC] = N_EDGES;
}

// ---------------------------------------------------------------------------
// Phase 3: bin edges into per-(vxcd, dst) segments.
// ---------------------------------------------------------------------------
__global__ __launch_bounds__(256) void bin_kernel(
    const int* __restrict__ ei, const float* __restrict__ ew,
    const int* __restrict__ offset, int* __restrict__ count,
    int2* __restrict__ bucket)
{
    int e = blockIdx.x * 256 + threadIdx.x;
    if (e >= N_EDGES) return;
    int   vx  = blockIdx.x & 7;
    int   dst = ei[e];
    int   src = ei[N_EDGES + e];
    float w   = ew[e];
    int   idx = vx * N_NODES + dst;
    int pos = atomicAdd(&count[idx], -1) - 1;
    bucket[offset[idx] + pos] = make_int2(src, __float_as_int(w));
}

// ---------------------------------------------------------------------------
// Phase 4: one WAVE per node. Lanes 0..15 load all 16 segment boundaries in
// one shot; subgroup sg (lanes 16sg..16sg+15) accumulates segments vx=sg and
// vx=sg+4 in registers (4 concurrent gather chains per node). Cross-subgroup
// reduce via shfl_xor; lanes 0..15 write the 64-ch row.
// ---------------------------------------------------------------------------
__global__ __launch_bounds__(256) void agg_kernel(
    const float* __restrict__ x, const int2* __restrict__ bucket,
    const int* __restrict__ offset, float* __restrict__ agg)
{
    const int lane = threadIdx.x & 63;
    const int wid  = threadIdx.x >> 6;
    const int node = blockIdx.x * 4 + wid;
    if (node >= N_NODES) return;

    // lane l<16: vx = l>>1, which = l&1 -> offset[vx*N + node + which]
    int v_off = 0;
    if (lane < 16)
        v_off = offset[(lane >> 1) * N_NODES + node + (lane & 1)];

    const int sg = lane >> 4;
    const int c4 = (lane & 15) << 2;

    const int begA = __shfl(v_off, 2 * sg,           64);
    const int endA = __shfl(v_off, 2 * sg + 1,       64);
    const int begB = __shfl(v_off, 2 * (sg + 4),     64);
    const int endB = __shfl(v_off, 2 * (sg + 4) + 1, 64);

    float4 acc = make_float4(0.f, 0.f, 0.f, 0.f);
    for (int j = begA; j < endA; ++j) {
        int2  eb = bucket[j];
        float w  = __int_as_float(eb.y);
        float4 v = *reinterpret_cast<const float4*>(x + (size_t)eb.x * IN_CH + c4);
        acc.x += w * v.x; acc.y += w * v.y; acc.z += w * v.z; acc.w += w * v.w;
    }
    for (int j = begB; j < endB; ++j) {
        int2  eb = bucket[j];
        float w  = __int_as_float(eb.y);
        float4 v = *reinterpret_cast<const float4*>(x + (size_t)eb.x * IN_CH + c4);
        acc.x += w * v.x; acc.y += w * v.y; acc.z += w * v.z; acc.w += w * v.w;
    }

    // reduce across the 4 subgroups (lanes l, l^16, l^32, l^48)
    acc.x += __shfl_xor(acc.x, 16, 64);
    acc.y += __shfl_xor(acc.y, 16, 64);
    acc.z += __shfl_xor(acc.z, 16, 64);
    acc.w += __shfl_xor(acc.w, 16, 64);
    acc.x += __shfl_xor(acc.x, 32, 64);
    acc.y += __shfl_xor(acc.y, 32, 64);
    acc.z += __shfl_xor(acc.z, 32, 64);
    acc.w += __shfl_xor(acc.w, 32, 64);

    if (lane < 16)
        *reinterpret_cast<float4*>(agg + (size_t)node * IN_CH + c4) = acc;
}

// ---------------------------------------------------------------------------
// Phase 5: out[N,128] = agg[N,64] @ W[128,64]^T + b
// ---------------------------------------------------------------------------
constexpr int LSTR = 66;

__global__ __launch_bounds__(256) void gcn_gemm_kernel(
    const float* __restrict__ agg,
    const float* __restrict__ W,
    const float* __restrict__ b,
    float*       __restrict__ out)
{
    __shared__ float Wl[OUT_CH * LSTR];
    __shared__ float al[32 * LSTR];

    const int t = threadIdx.x;
    const int rbase = blockIdx.x * 32;

    for (int i = t; i < OUT_CH * IN_CH / 4; i += 256) {
        float4 v = reinterpret_cast<const float4*>(W)[i];
        int c = i >> 4;
        int k = (i & 15) << 2;
        float* p = &Wl[c * LSTR + k];
        p[0] = v.x; p[1] = v.y; p[2] = v.z; p[3] = v.w;
    }
    for (int i = t; i < 32 * IN_CH / 4; i += 256) {
        float4 v = reinterpret_cast<const float4*>(agg + (size_t)rbase * IN_CH)[i];
        int r = i >> 4;
        int k = (i & 15) << 2;
        float* p = &al[r * LSTR + k];
        p[0] = v.x; p[1] = v.y; p[2] = v.z; p[3] = v.w;
    }
    __syncthreads();

    const int chT = t & 31;
    const int r0  = (t >> 5) << 2;

    float acc[4][4];
    #pragma unroll
    for (int i = 0; i < 4; ++i)
        #pragma unroll
        for (int j = 0; j < 4; ++j)
            acc[i][j] = 0.f;

    #pragma unroll
    for (int k = 0; k < IN_CH; k += 2) {
        float2 wv[4], av[4];
        #pragma unroll
        for (int j = 0; j < 4; ++j)
            wv[j] = *reinterpret_cast<const float2*>(&Wl[(chT + 32 * j) * LSTR + k]);
        #pragma unroll
        for (int i = 0; i < 4; ++i)
            av[i] = *reinterpret_cast<const float2*>(&al[(r0 + i) * LSTR + k]);
        #pragma unroll
        for (int i = 0; i < 4; ++i)
            #pragma unroll
            for (int j = 0; j < 4; ++j)
                acc[i][j] += av[i].x * wv[j].x + av[i].y * wv[j].y;
    }

    #pragma unroll
    for (int j = 0; j < 4; ++j) {
        int   c  = chT + 32 * j;
        float bc = b[c];
        #pragma unroll
        for (int i = 0; i < 4; ++i) {
            int r = rbase + r0 + i;
            out[(size_t)r * OUT_CH + c] = acc[i][j] + bc;
        }
    }
}

// ---------------------------------------------------------------------------
extern "C" void kernel_launch(void* const* d_in, const int* in_sizes, int n_in,
                              void* d_out, int out_size, void* d_ws, size_t ws_size,
                              hipStream_t stream) {
    const float* x  = (const float*)d_in[0];
    const int*   ei = (const int*)  d_in[1];
    const float* ew = (const float*)d_in[2];
    const float* W  = (const float*)d_in[3];
    const float* b  = (const float*)d_in[4];
    float* out = (float*)d_out;

    char* ws = (char*)d_ws;
    size_t off = 0;
    auto alloc = [&](size_t bytes) {
        char* p = ws + off;
        off += (bytes + 15) & ~size_t(15);
        return p;
    };
    float* agg      = (float*)alloc((size_t)N_NODES * IN_CH * sizeof(float)); // 25.6 MB
    int*   count    = (int*)  alloc((size_t)NC * sizeof(int));                // 3.2 MB
    int*   offset   = (int*)  alloc((size_t)(NC + 1) * sizeof(int));          // 3.2 MB
    int*   partials = (int*)  alloc(1024 * sizeof(int));
    int2*  bucket   = (int2*) alloc((size_t)N_EDGES * sizeof(int2));          // 8 MB

    hipMemsetAsync(count, 0, (size_t)NC * sizeof(int), stream);

    int egrid = (N_EDGES + 255) / 256;
    hist_kernel<<<egrid, 256, 0, stream>>>(ei, count);
    scanA_kernel<<<SCAN_BLOCKS, 256, 0, stream>>>(count, offset, partials);
    scanB_kernel<<<1, 1024, 0, stream>>>(partials);
    scanC_kernel<<<(NC + 255) / 256, 256, 0, stream>>>(offset, partials);
    bin_kernel<<<egrid, 256, 0, stream>>>(ei, ew, offset, count, bucket);

    agg_kernel<<<(N_NODES + 3) / 4, 256, 0, stream>>>(x, bucket, offset, agg);

    gcn_gemm_kernel<<<N_NODES / 32, 256, 0, stream>>>(agg, W, b, out);
}

// Round 7
// 200.794 us; speedup vs baseline: 2.4295x; 1.0404x over previous
//
#include <hip/hip_runtime.h>

constexpr int N_NODES = 100000;
constexpr int N_EDGES = 1000000;
constexpr int IN_CH   = 64;
constexpr int OUT_CH  = 128;

constexpr int NVX = 8;                       // virtual XCDs
constexpr int NC  = NVX * N_NODES;           // 800000 (vxcd, dst) counters

constexpr int SCAN_ELEMS  = 1024;
constexpr int SCAN_BLOCKS = (NC + SCAN_ELEMS - 1) / SCAN_ELEMS;   // 782

typedef __attribute__((ext_vector_type(4))) float f32x4;
typedef __attribute__((ext_vector_type(8))) short s16x8;

__device__ inline ushort bf16rn(float f) {
    unsigned u = __float_as_uint(f);
    u += 0x7FFF + ((u >> 16) & 1);           // round-to-nearest-even
    return (ushort)(u >> 16);
}
__device__ inline float bf2f(ushort s) {
    return __uint_as_float(((unsigned)s) << 16);
}

// ---------------------------------------------------------------------------
// Prepass: pack x (and W) to bf16. Halves the random-gather traffic.
// ---------------------------------------------------------------------------
__global__ __launch_bounds__(256) void cvt_x_kernel(
    const float* __restrict__ x, ushort* __restrict__ xb)
{
    int i = blockIdx.x * 256 + threadIdx.x;           // one float4 per thread
    if (i >= N_NODES * IN_CH / 4) return;
    float4 v = reinterpret_cast<const float4*>(x)[i];
    ushort4 o;
    o.x = bf16rn(v.x); o.y = bf16rn(v.y); o.z = bf16rn(v.z); o.w = bf16rn(v.w);
    reinterpret_cast<ushort4*>(xb)[i] = o;
}

__global__ __launch_bounds__(256) void cvt_w_kernel(
    const float* __restrict__ W, ushort* __restrict__ Wb)
{
    int i = blockIdx.x * 256 + threadIdx.x;
    if (i >= OUT_CH * IN_CH / 4) return;
    float4 v = reinterpret_cast<const float4*>(W)[i];
    ushort4 o;
    o.x = bf16rn(v.x); o.y = bf16rn(v.y); o.z = bf16rn(v.z); o.w = bf16rn(v.w);
    reinterpret_cast<ushort4*>(Wb)[i] = o;
}

// ---------------------------------------------------------------------------
// Phase 1: histogram over (vxcd, dst). vxcd = blockIdx%8 matches bin_kernel.
// ---------------------------------------------------------------------------
__global__ __launch_bounds__(256) void hist_kernel(
    const int* __restrict__ ei, int* __restrict__ count)
{
    int e = blockIdx.x * 256 + threadIdx.x;
    if (e >= N_EDGES) return;
    int vx = blockIdx.x & 7;
    atomicAdd(&count[vx * N_NODES + ei[e]], 1);
}

// ---------------------------------------------------------------------------
// Phase 2: hierarchical exclusive scan of count[0..NC) -> offset[0..NC].
// ---------------------------------------------------------------------------
__global__ __launch_bounds__(256) void scanA_kernel(
    const int* __restrict__ count, int* __restrict__ offset,
    int* __restrict__ partials)
{
    __shared__ int ts[256];
    const int t    = threadIdx.x;
    const int base = blockIdx.x * SCAN_ELEMS + t * 4;

    int v[4], s = 0;
    #pragma unroll
    for (int j = 0; j < 4; ++j) {
        int i = base + j;
        v[j] = (i < NC) ? count[i] : 0;
        s += v[j];
    }
    ts[t] = s;
    __syncthreads();
    for (int off = 1; off < 256; off <<= 1) {
        int add = (t >= off) ? ts[t - off] : 0;
        __syncthreads();
        ts[t] += add;
        __syncthreads();
    }
    int run = ts[t] - s;
    #pragma unroll
    for (int j = 0; j < 4; ++j) {
        int i = base + j;
        if (i < NC) offset[i] = run;
        run += v[j];
    }
    if (t == 255) partials[blockIdx.x] = ts[255];
}

__global__ __launch_bounds__(1024) void scanB_kernel(int* __restrict__ partials)
{
    __shared__ int ts[1024];
    const int t = threadIdx.x;
    int v = (t < SCAN_BLOCKS) ? partials[t] : 0;
    ts[t] = v;
    __syncthreads();
    for (int off = 1; off < 1024; off <<= 1) {
        int add = (t >= off) ? ts[t - off] : 0;
        __syncthreads();
        ts[t] += add;
        __syncthreads();
    }
    if (t < SCAN_BLOCKS) partials[t] = ts[t] - v;   // exclusive
}

__global__ __launch_bounds__(256) void scanC_kernel(
    int* __restrict__ offset, const int* __restrict__ partials)
{
    int i = blockIdx.x * 256 + threadIdx.x;
    if (i < NC) offset[i] += partials[i >> 10];
    if (i == 0) offset[NC] = N_EDGES;
}

// ---------------------------------------------------------------------------
// Phase 3: bin edges into per-(vxcd, dst) segments.
// ---------------------------------------------------------------------------
__global__ __launch_bounds__(256) void bin_kernel(
    const int* __restrict__ ei, const float* __restrict__ ew,
    const int* __restrict__ offset, int* __restrict__ count,
    int2* __restrict__ bucket)
{
    int e = blockIdx.x * 256 + threadIdx.x;
    if (e >= N_EDGES) return;
    int   vx  = blockIdx.x & 7;
    int   dst = ei[e];
    int   src = ei[N_EDGES + e];
    float w   = ew[e];
    int   idx = vx * N_NODES + dst;
    int pos = atomicAdd(&count[idx], -1) - 1;
    bucket[offset[idx] + pos] = make_int2(src, __float_as_int(w));
}

// ---------------------------------------------------------------------------
// Phase 4: one WAVE per node; 4 subgroups each own 2 of the 8 vx-segments.
// bf16 gathers (128 B/edge). Accumulate fp32, write bf16 agg row.
// ---------------------------------------------------------------------------
__global__ __launch_bounds__(256) void agg_kernel(
    const ushort* __restrict__ xb, const int2* __restrict__ bucket,
    const int* __restrict__ offset, ushort* __restrict__ aggb)
{
    const int lane = threadIdx.x & 63;
    const int wid  = threadIdx.x >> 6;
    const int node = blockIdx.x * 4 + wid;
    if (node >= N_NODES) return;

    int v_off = 0;
    if (lane < 16)
        v_off = offset[(lane >> 1) * N_NODES + node + (lane & 1)];

    const int sg = lane >> 4;
    const int q  = lane & 15;                 // channel quad index

    const int begA = __shfl(v_off, 2 * sg,           64);
    const int endA = __shfl(v_off, 2 * sg + 1,       64);
    const int begB = __shfl(v_off, 2 * (sg + 4),     64);
    const int endB = __shfl(v_off, 2 * (sg + 4) + 1, 64);

    float4 acc = make_float4(0.f, 0.f, 0.f, 0.f);
    for (int j = begA; j < endA; ++j) {
        int2  eb = bucket[j];
        float w  = __int_as_float(eb.y);
        ushort4 s = reinterpret_cast<const ushort4*>(xb + (size_t)eb.x * IN_CH)[q];
        acc.x += w * bf2f(s.x); acc.y += w * bf2f(s.y);
        acc.z += w * bf2f(s.z); acc.w += w * bf2f(s.w);
    }
    for (int j = begB; j < endB; ++j) {
        int2  eb = bucket[j];
        float w  = __int_as_float(eb.y);
        ushort4 s = reinterpret_cast<const ushort4*>(xb + (size_t)eb.x * IN_CH)[q];
        acc.x += w * bf2f(s.x); acc.y += w * bf2f(s.y);
        acc.z += w * bf2f(s.z); acc.w += w * bf2f(s.w);
    }

    acc.x += __shfl_xor(acc.x, 16, 64);
    acc.y += __shfl_xor(acc.y, 16, 64);
    acc.z += __shfl_xor(acc.z, 16, 64);
    acc.w += __shfl_xor(acc.w, 16, 64);
    acc.x += __shfl_xor(acc.x, 32, 64);
    acc.y += __shfl_xor(acc.y, 32, 64);
    acc.z += __shfl_xor(acc.z, 32, 64);
    acc.w += __shfl_xor(acc.w, 32, 64);

    if (lane < 16) {
        ushort4 o;
        o.x = bf16rn(acc.x); o.y = bf16rn(acc.y);
        o.z = bf16rn(acc.z); o.w = bf16rn(acc.w);
        reinterpret_cast<ushort4*>(aggb + (size_t)node * IN_CH)[q] = o;
    }
}

// ---------------------------------------------------------------------------
// Phase 5: out[N,128] = aggb[N,64] @ Wb[128,64]^T + b via MFMA bf16.
// Wave handles 16 rows x 128 cols: 8 col-tiles x 2 K-steps.
// A: row=lane&15, k=(lane>>4)*8+e.  B: col=lane&15, same k.
// D: col=lane&15, row=(lane>>4)*4+reg  [m89-verified layout].
// ---------------------------------------------------------------------------
__global__ __launch_bounds__(256) void gemm_kernel(
    const ushort* __restrict__ aggb, const ushort* __restrict__ Wb,
    const float* __restrict__ b, float* __restrict__ out)
{
    const int lane  = threadIdx.x & 63;
    const int wid   = threadIdx.x >> 6;
    const int rbase = blockIdx.x * 64 + wid * 16;

    const int rA = rbase + (lane & 15);
    const int kA = (lane >> 4) * 8;
    const int rAc = (rA < N_NODES) ? rA : 0;

    s16x8 a0 = *reinterpret_cast<const s16x8*>(aggb + (size_t)rAc * IN_CH + kA);
    s16x8 a1 = *reinterpret_cast<const s16x8*>(aggb + (size_t)rAc * IN_CH + kA + 32);

    f32x4 acc[8];
    #pragma unroll
    for (int t = 0; t < 8; ++t) acc[t] = (f32x4)(0.f);

    #pragma unroll
    for (int t = 0; t < 8; ++t) {
        int c = t * 16 + (lane & 15);
        s16x8 b0 = *reinterpret_cast<const s16x8*>(Wb + (size_t)c * IN_CH + kA);
        s16x8 b1 = *reinterpret_cast<const s16x8*>(Wb + (size_t)c * IN_CH + kA + 32);
        acc[t] = __builtin_amdgcn_mfma_f32_16x16x32_bf16(a0, b0, acc[t], 0, 0, 0);
        acc[t] = __builtin_amdgcn_mfma_f32_16x16x32_bf16(a1, b1, acc[t], 0, 0, 0);
    }

    const int colL   = lane & 15;
    const int rowOff = (lane >> 4) * 4;
    #pragma unroll
    for (int t = 0; t < 8; ++t) {
        int   c  = t * 16 + colL;
        float bc = b[c];
        #pragma unroll
        for (int i = 0; i < 4; ++i) {
            int r = rbase + rowOff + i;
            if (r < N_NODES)
                out[(size_t)r * OUT_CH + c] = acc[t][i] + bc;
        }
    }
}

// ---------------------------------------------------------------------------
extern "C" void kernel_launch(void* const* d_in, const int* in_sizes, int n_in,
                              void* d_out, int out_size, void* d_ws, size_t ws_size,
                              hipStream_t stream) {
    const float* x  = (const float*)d_in[0];
    const int*   ei = (const int*)  d_in[1];
    const float* ew = (const float*)d_in[2];
    const float* W  = (const float*)d_in[3];
    const float* b  = (const float*)d_in[4];
    float* out = (float*)d_out;

    char* ws = (char*)d_ws;
    size_t off = 0;
    auto alloc = [&](size_t bytes) {
        char* p = ws + off;
        off += (bytes + 15) & ~size_t(15);
        return p;
    };
    ushort* xb       = (ushort*)alloc((size_t)N_NODES * IN_CH * sizeof(ushort)); // 12.8 MB
    ushort* aggb     = (ushort*)alloc((size_t)N_NODES * IN_CH * sizeof(ushort)); // 12.8 MB
    ushort* Wb       = (ushort*)alloc((size_t)OUT_CH * IN_CH * sizeof(ushort));  // 16 KB
    int*    count    = (int*)   alloc((size_t)NC * sizeof(int));                 // 3.2 MB
    int*    offset   = (int*)   alloc((size_t)(NC + 1) * sizeof(int));           // 3.2 MB
    int*    partials = (int*)   alloc(1024 * sizeof(int));
    int2*   bucket   = (int2*)  alloc((size_t)N_EDGES * sizeof(int2));           // 8 MB

    hipMemsetAsync(count, 0, (size_t)NC * sizeof(int), stream);

    cvt_x_kernel<<<(N_NODES * IN_CH / 4 + 255) / 256, 256, 0, stream>>>(x, xb);
    cvt_w_kernel<<<(OUT_CH * IN_CH / 4 + 255) / 256, 256, 0, stream>>>(W, Wb);

    int egrid = (N_EDGES + 255) / 256;
    hist_kernel<<<egrid, 256, 0, stream>>>(ei, count);
    scanA_kernel<<<SCAN_BLOCKS, 256, 0, stream>>>(count, offset, partials);
    scanB_kernel<<<1, 1024, 0, stream>>>(partials);
    scanC_kernel<<<(NC + 255) / 256, 256, 0, stream>>>(offset, partials);
    bin_kernel<<<egrid, 256, 0, stream>>>(ei, ew, offset, count, bucket);

    agg_kernel<<<(N_NODES + 3) / 4, 256, 0, stream>>>(xb, bucket, offset, aggb);

    gemm_kernel<<<(N_NODES + 63) / 64, 256, 0, stream>>>(aggb, Wb, b, out);
}

// Round 8
// 182.698 us; speedup vs baseline: 2.6701x; 1.0990x over previous
//
#include <hip/hip_runtime.h>

constexpr int N_NODES = 100000;
constexpr int N_EDGES = 1000000;
constexpr int IN_CH   = 64;
constexpr int OUT_CH  = 128;

constexpr int NVX = 8;                       // virtual XCDs
constexpr int NC  = NVX * N_NODES;           // 800000 (vxcd, dst) counters

constexpr int SCAN_ELEMS  = 1024;
constexpr int SCAN_BLOCKS = (NC + SCAN_ELEMS - 1) / SCAN_ELEMS;   // 782

typedef __attribute__((ext_vector_type(4))) float f32x4;
typedef __attribute__((ext_vector_type(8))) short s16x8;

__device__ inline ushort bf16rn(float f) {
    unsigned u = __float_as_uint(f);
    u += 0x7FFF + ((u >> 16) & 1);           // round-to-nearest-even
    return (ushort)(u >> 16);
}
__device__ inline float bf2f(ushort s) {
    return __uint_as_float(((unsigned)s) << 16);
}

// ---------------------------------------------------------------------------
// Prepass: pack x and W to bf16.
// ---------------------------------------------------------------------------
__global__ __launch_bounds__(256) void cvt_x_kernel(
    const float* __restrict__ x, ushort* __restrict__ xb)
{
    int i = blockIdx.x * 256 + threadIdx.x;
    if (i >= N_NODES * IN_CH / 4) return;
    float4 v = reinterpret_cast<const float4*>(x)[i];
    ushort4 o;
    o.x = bf16rn(v.x); o.y = bf16rn(v.y); o.z = bf16rn(v.z); o.w = bf16rn(v.w);
    reinterpret_cast<ushort4*>(xb)[i] = o;
}

__global__ __launch_bounds__(256) void cvt_w_kernel(
    const float* __restrict__ W, ushort* __restrict__ Wb)
{
    int i = blockIdx.x * 256 + threadIdx.x;
    if (i >= OUT_CH * IN_CH / 4) return;
    float4 v = reinterpret_cast<const float4*>(W)[i];
    ushort4 o;
    o.x = bf16rn(v.x); o.y = bf16rn(v.y); o.z = bf16rn(v.z); o.w = bf16rn(v.w);
    reinterpret_cast<ushort4*>(Wb)[i] = o;
}

// ---------------------------------------------------------------------------
// Phase 1: histogram over (vxcd, dst). vxcd = blockIdx%8 matches bin_kernel.
// ---------------------------------------------------------------------------
__global__ __launch_bounds__(256) void hist_kernel(
    const int* __restrict__ ei, int* __restrict__ count)
{
    int e = blockIdx.x * 256 + threadIdx.x;
    if (e >= N_EDGES) return;
    int vx = blockIdx.x & 7;
    atomicAdd(&count[vx * N_NODES + ei[e]], 1);
}

// ---------------------------------------------------------------------------
// Phase 2: hierarchical exclusive scan of count[0..NC) -> offset[0..NC].
// scanC also materializes cursor = offset for bin's bump-allocator.
// ---------------------------------------------------------------------------
__global__ __launch_bounds__(256) void scanA_kernel(
    const int* __restrict__ count, int* __restrict__ offset,
    int* __restrict__ partials)
{
    __shared__ int ts[256];
    const int t    = threadIdx.x;
    const int base = blockIdx.x * SCAN_ELEMS + t * 4;

    int v[4], s = 0;
    #pragma unroll
    for (int j = 0; j < 4; ++j) {
        int i = base + j;
        v[j] = (i < NC) ? count[i] : 0;
        s += v[j];
    }
    ts[t] = s;
    __syncthreads();
    for (int off = 1; off < 256; off <<= 1) {
        int add = (t >= off) ? ts[t - off] : 0;
        __syncthreads();
        ts[t] += add;
        __syncthreads();
    }
    int run = ts[t] - s;
    #pragma unroll
    for (int j = 0; j < 4; ++j) {
        int i = base + j;
        if (i < NC) offset[i] = run;
        run += v[j];
    }
    if (t == 255) partials[blockIdx.x] = ts[255];
}

__global__ __launch_bounds__(1024) void scanB_kernel(int* __restrict__ partials)
{
    __shared__ int ts[1024];
    const int t = threadIdx.x;
    int v = (t < SCAN_BLOCKS) ? partials[t] : 0;
    ts[t] = v;
    __syncthreads();
    for (int off = 1; off < 1024; off <<= 1) {
        int add = (t >= off) ? ts[t - off] : 0;
        __syncthreads();
        ts[t] += add;
        __syncthreads();
    }
    if (t < SCAN_BLOCKS) partials[t] = ts[t] - v;   // exclusive
}

__global__ __launch_bounds__(256) void scanC_kernel(
    int* __restrict__ offset, const int* __restrict__ partials,
    int* __restrict__ cursor)
{
    int i = blockIdx.x * 256 + threadIdx.x;
    if (i < NC) {
        int o = offset[i] + partials[i >> 10];
        offset[i] = o;
        cursor[i] = o;
    }
    if (i == 0) offset[NC] = N_EDGES;
}

// ---------------------------------------------------------------------------
// Phase 3: bin edges. One random atomic (bump cursor) per edge; position is
// the returned value directly — no offset read, no down-counter.
// ---------------------------------------------------------------------------
__global__ __launch_bounds__(256) void bin_kernel(
    const int* __restrict__ ei, const float* __restrict__ ew,
    int* __restrict__ cursor, int2* __restrict__ bucket)
{
    int e = blockIdx.x * 256 + threadIdx.x;
    if (e >= N_EDGES) return;
    int   vx  = blockIdx.x & 7;
    int   dst = ei[e];
    int   src = ei[N_EDGES + e];
    float w   = ew[e];
    int   idx = vx * N_NODES + dst;
    int   pos = atomicAdd(&cursor[idx], 1);
    bucket[pos] = make_int2(src, __float_as_int(w));
}

// ---------------------------------------------------------------------------
// Phase 4 (fused agg + GEMM): block = 1024 thr = 16 waves = 16 nodes.
// Per wave: 8 groups of 8 lanes, group g owns vx-segment g (depth ~1.25,
// 8 concurrent gather chains). ushort8 (16B) gather per lane. Reduce via
// 3x shfl_xor, stage 16x64 bf16 rows in swizzled LDS, then waves 0-3 do the
// 16-row x 128-col MFMA GEMM and write out directly.
// ---------------------------------------------------------------------------
__global__ __launch_bounds__(1024) void agg_gemm_kernel(
    const ushort* __restrict__ xb, const int2* __restrict__ bucket,
    const int* __restrict__ offset, const ushort* __restrict__ Wb,
    const float* __restrict__ b, float* __restrict__ out)
{
    __shared__ ushort rowt[16 * IN_CH];       // 2 KB, XOR-swizzled

    const int t    = threadIdx.x;
    const int lane = t & 63;
    const int wv   = t >> 6;                  // 0..15 = node-in-tile
    const int node = blockIdx.x * 16 + wv;    // grid exact: 6250*16 = 100000

    int v_off = 0;
    if (lane < 16)
        v_off = offset[(lane >> 1) * N_NODES + node + (lane & 1)];

    const int g  = lane >> 3;                 // segment group 0..7
    const int q8 = lane & 7;                  // channel octet 0..7
    const int beg = __shfl(v_off, 2 * g,     64);
    const int end = __shfl(v_off, 2 * g + 1, 64);

    float acc[8] = {0.f, 0.f, 0.f, 0.f, 0.f, 0.f, 0.f, 0.f};
    for (int j = beg; j < end; ++j) {
        int2  eb = bucket[j];
        float w  = __int_as_float(eb.y);
        s16x8 sv = *reinterpret_cast<const s16x8*>(
            xb + (size_t)eb.x * IN_CH + q8 * 8);
        #pragma unroll
        for (int c = 0; c < 8; ++c)
            acc[c] += w * bf2f((ushort)sv[c]);
    }

    // reduce across the 8 groups (same q8, lanes l^8, l^16, l^32)
    #pragma unroll
    for (int m = 8; m <= 32; m <<= 1)
        #pragma unroll
        for (int c = 0; c < 8; ++c)
            acc[c] += __shfl_xor(acc[c], m, 64);

    if (lane < 8) {
        s16x8 o;
        #pragma unroll
        for (int c = 0; c < 8; ++c)
            o[c] = (short)bf16rn(acc[c]);
        int byteoff = (wv * 128 + q8 * 16) ^ ((wv & 7) << 4);
        *reinterpret_cast<s16x8*>(reinterpret_cast<char*>(rowt) + byteoff) = o;
    }
    __syncthreads();

    if (wv < 4) {
        const int rbase = blockIdx.x * 16;
        const int colL  = lane & 15;
        const int kseg  = lane >> 4;          // 0..3
        const int arow  = colL;               // A row = node-in-tile
        int a0off = (arow * 128 + kseg * 16)      ^ ((arow & 7) << 4);
        int a1off = (arow * 128 + 64 + kseg * 16) ^ ((arow & 7) << 4);
        s16x8 a0 = *reinterpret_cast<const s16x8*>(
            reinterpret_cast<const char*>(rowt) + a0off);
        s16x8 a1 = *reinterpret_cast<const s16x8*>(
            reinterpret_cast<const char*>(rowt) + a1off);

        #pragma unroll
        for (int tt = 0; tt < 2; ++tt) {
            int c = (wv * 2 + tt) * 16 + colL;
            s16x8 b0 = *reinterpret_cast<const s16x8*>(
                Wb + (size_t)c * IN_CH + kseg * 8);
            s16x8 b1 = *reinterpret_cast<const s16x8*>(
                Wb + (size_t)c * IN_CH + kseg * 8 + 32);
            f32x4 d = (f32x4)(0.f);
            d = __builtin_amdgcn_mfma_f32_16x16x32_bf16(a0, b0, d, 0, 0, 0);
            d = __builtin_amdgcn_mfma_f32_16x16x32_bf16(a1, b1, d, 0, 0, 0);
            float bc = b[c];
            #pragma unroll
            for (int i = 0; i < 4; ++i) {
                int r = rbase + kseg * 4 + i;  // D row = (lane>>4)*4 + i
                out[(size_t)r * OUT_CH + c] = d[i] + bc;
            }
        }
    }
}

// ---------------------------------------------------------------------------
extern "C" void kernel_launch(void* const* d_in, const int* in_sizes, int n_in,
                              void* d_out, int out_size, void* d_ws, size_t ws_size,
                              hipStream_t stream) {
    const float* x  = (const float*)d_in[0];
    const int*   ei = (const int*)  d_in[1];
    const float* ew = (const float*)d_in[2];
    const float* W  = (const float*)d_in[3];
    const float* b  = (const float*)d_in[4];
    float* out = (float*)d_out;

    char* ws = (char*)d_ws;
    size_t off = 0;
    auto alloc = [&](size_t bytes) {
        char* p = ws + off;
        off += (bytes + 15) & ~size_t(15);
        return p;
    };
    ushort* xb       = (ushort*)alloc((size_t)N_NODES * IN_CH * sizeof(ushort)); // 12.8 MB
    ushort* Wb       = (ushort*)alloc((size_t)OUT_CH * IN_CH * sizeof(ushort));  // 16 KB
    int*    count    = (int*)   alloc((size_t)NC * sizeof(int));                 // 3.2 MB
    int*    offset   = (int*)   alloc((size_t)(NC + 1) * sizeof(int));           // 3.2 MB
    int*    cursor   = (int*)   alloc((size_t)NC * sizeof(int));                 // 3.2 MB
    int*    partials = (int*)   alloc(1024 * sizeof(int));
    int2*   bucket   = (int2*)  alloc((size_t)N_EDGES * sizeof(int2));           // 8 MB

    hipMemsetAsync(count, 0, (size_t)NC * sizeof(int), stream);

    cvt_x_kernel<<<(N_NODES * IN_CH / 4 + 255) / 256, 256, 0, stream>>>(x, xb);
    cvt_w_kernel<<<(OUT_CH * IN_CH / 4 + 255) / 256, 256, 0, stream>>>(W, Wb);

    int egrid = (N_EDGES + 255) / 256;
    hist_kernel<<<egrid, 256, 0, stream>>>(ei, count);
    scanA_kernel<<<SCAN_BLOCKS, 256, 0, stream>>>(count, offset, partials);
    scanB_kernel<<<1, 1024, 0, stream>>>(partials);
    scanC_kernel<<<(NC + 255) / 256, 256, 0, stream>>>(offset, partials, cursor);
    bin_kernel<<<egrid, 256, 0, stream>>>(ei, ew, cursor, bucket);

    agg_gemm_kernel<<<N_NODES / 16, 1024, 0, stream>>>(
        xb, bucket, offset, Wb, b, out);
}